// Round 1
// baseline (178.972 us; speedup 1.0000x reference)
//
#include <hip/hip_runtime.h>
#include <math.h>

#define VOCAB 128000
#define DIM   2048
#define TOPK  50
#define NBINS 8192
#define CAP   2048
#define NTHR  256

__global__ __launch_bounds__(NTHR, 2) void softmix_kernel(
    const float* __restrict__ logits,   // [ROWS, VOCAB]
    const float* __restrict__ emb,      // [VOCAB, DIM]
    float* __restrict__ out)            // [ROWS, DIM]
{
    __shared__ unsigned int hist[NBINS];
    __shared__ float cand_v[CAP];
    __shared__ int   cand_i[CAP];
    __shared__ unsigned int cand_cnt;
    __shared__ unsigned int seg[NTHR];
    __shared__ unsigned int binStar;
    __shared__ float sel_v[TOPK];
    __shared__ int   sel_i[TOPK];
    __shared__ float sel_w[TOPK];
    __shared__ float wsum;

    const int row = blockIdx.x;
    const int t   = threadIdx.x;
    const float4* lrow = (const float4*)(logits + (size_t)row * VOCAB);
    const int n4 = VOCAB / 4;  // 32000

    for (int i = t; i < NBINS; i += NTHR) hist[i] = 0u;
    if (t == 0) cand_cnt = 0u;
    __syncthreads();

    // ---- pass 1: 13-bit histogram of order-preserving float keys ----
    for (int p = t; p < n4; p += NTHR) {
        float4 v = lrow[p];
        #pragma unroll
        for (int j = 0; j < 4; ++j) {
            float f = (&v.x)[j];
            unsigned u = __float_as_uint(f);
            unsigned key = (u & 0x80000000u) ? ~u : (u | 0x80000000u);
            atomicAdd(&hist[key >> 19], 1u);
        }
    }
    __syncthreads();

    // ---- find critical bin: smallest set of top bins holding >= TOPK ----
    {
        const int per = NBINS / NTHR;          // 32 bins per thread
        const int base = t * per;
        unsigned s = 0;
        for (int i = 0; i < per; ++i) s += hist[base + i];
        seg[t] = s;
        __syncthreads();
        unsigned suff = 0;
        for (int j = NTHR - 1; j > t; --j) suff += seg[j];
        // exactly one thread's segment contains the crossing
        if (suff < TOPK && suff + seg[t] >= TOPK) {
            unsigned running = suff;
            for (int b = per - 1; b >= 0; --b) {
                unsigned c = hist[base + b];
                if (running + c >= TOPK) { binStar = (unsigned)(base + b); break; }
                running += c;
            }
        }
    }
    __syncthreads();
    const unsigned bstar = binStar;

    // ---- pass 2: collect candidates (all elements with bin >= bstar) ----
    for (int p = t; p < n4; p += NTHR) {
        float4 v = lrow[p];
        #pragma unroll
        for (int j = 0; j < 4; ++j) {
            float f = (&v.x)[j];
            unsigned u = __float_as_uint(f);
            unsigned key = (u & 0x80000000u) ? ~u : (u | 0x80000000u);
            if ((key >> 19) >= bstar) {
                unsigned pos = atomicAdd(&cand_cnt, 1u);
                if (pos < CAP) { cand_v[pos] = f; cand_i[pos] = 4 * p + j; }
            }
        }
    }
    __syncthreads();

    const int C = (cand_cnt < (unsigned)CAP) ? (int)cand_cnt : CAP;

    // ---- exact rank selection; tie-break = lower index wins (lax.top_k) ----
    for (int i = t; i < C; i += NTHR) {
        float vi = cand_v[i]; int ii = cand_i[i];
        int rank = 0;
        for (int j = 0; j < C; ++j) {
            float vj = cand_v[j]; int ij = cand_i[j];
            rank += (int)((vj > vi) || (vj == vi && ij < ii));
        }
        if (rank < TOPK) { sel_v[rank] = vi; sel_i[rank] = ii; }
    }
    __syncthreads();

    // ---- weights: exp(v - max), sum over top-k (global softmax Z cancels) ----
    if (t < 64) {
        float p = 0.f;
        if (t < TOPK) { p = expf(sel_v[t] - sel_v[0]); sel_w[t] = p; }
        for (int off = 32; off; off >>= 1) p += __shfl_down(p, off);
        if (t == 0) wsum = p;
    }
    __syncthreads();
    const float inv = 1.0f / wsum;

    // ---- gather + weighted accumulate: thread t owns float4 slots t and t+256 ----
    float4 a0 = {0.f, 0.f, 0.f, 0.f};
    float4 a1 = {0.f, 0.f, 0.f, 0.f};
    for (int k = 0; k < TOPK; ++k) {
        const float w = sel_w[k];
        const float4* erow = (const float4*)(emb + (size_t)sel_i[k] * DIM);
        float4 e0 = erow[t];
        float4 e1 = erow[t + NTHR];
        a0.x += w * e0.x; a0.y += w * e0.y; a0.z += w * e0.z; a0.w += w * e0.w;
        a1.x += w * e1.x; a1.y += w * e1.y; a1.z += w * e1.z; a1.w += w * e1.w;
    }
    a0.x *= inv; a0.y *= inv; a0.z *= inv; a0.w *= inv;
    a1.x *= inv; a1.y *= inv; a1.z *= inv; a1.w *= inv;

    float4* orow = (float4*)(out + (size_t)row * DIM);
    orow[t]        = a0;
    orow[t + NTHR] = a1;
}

extern "C" void kernel_launch(void* const* d_in, const int* in_sizes, int n_in,
                              void* d_out, int out_size, void* d_ws, size_t ws_size,
                              hipStream_t stream) {
    const float* logits = (const float*)d_in[0];
    const float* emb    = (const float*)d_in[1];
    float* out = (float*)d_out;
    const int rows = in_sizes[0] / VOCAB;   // B*T = 512
    softmix_kernel<<<rows, NTHR, 0, stream>>>(logits, emb, out);
}

// Round 2
// 123.453 us; speedup vs baseline: 1.4497x; 1.4497x over previous
//
#include <hip/hip_runtime.h>
#include <math.h>

#define VOCAB  128000
#define DIM    2048
#define TOPK   50
#define NTHR   256
#define CAP    512
#define NBINS  4096
#define THRESH 3.0f

typedef float f4 __attribute__((ext_vector_type(4)));

__global__ __launch_bounds__(NTHR) void softmix_kernel(
    const float* __restrict__ logits,   // [ROWS, VOCAB]
    const float* __restrict__ emb,      // [VOCAB, DIM]
    float* __restrict__ out)            // [ROWS, DIM]
{
    __shared__ float cand_v[CAP];
    __shared__ int   cand_i[CAP];
    __shared__ unsigned int cand_cnt;
    __shared__ float sel_v[TOPK];
    __shared__ int   sel_i[TOPK];
    __shared__ float sel_w[TOPK];
    __shared__ float wsum;
    // fallback-only storage (unused on the fast path)
    __shared__ unsigned int hist[NBINS];
    __shared__ unsigned int seg[NTHR];
    __shared__ unsigned int binStar;

    const int row = blockIdx.x;
    const int t   = threadIdx.x;
    const f4* lrow = (const f4*)(logits + (size_t)row * VOCAB);
    const int n4 = VOCAB / 4;  // 32000

    if (t == 0) cand_cnt = 0u;
    __syncthreads();

    // ---- single streaming pass: collect everything >= THRESH ----
    // nontemporal: don't let the 262MB logits stream evict emb rows from L2/L3
    for (int p = t; p < n4; p += NTHR) {
        f4 v = __builtin_nontemporal_load(lrow + p);
        #pragma unroll
        for (int j = 0; j < 4; ++j) {
            float f = v[j];
            if (f >= THRESH) {
                unsigned pos = atomicAdd(&cand_cnt, 1u);
                if (pos < CAP) { cand_v[pos] = f; cand_i[pos] = 4 * p + j; }
            }
        }
    }
    __syncthreads();

    int C = (int)cand_cnt;

    // ---- fallback (exact, any-input-correct): histogram select ----
    if (C < TOPK || C > CAP) {
        for (int i = t; i < NBINS; i += NTHR) hist[i] = 0u;
        if (t == 0) cand_cnt = 0u;
        __syncthreads();
        for (int p = t; p < n4; p += NTHR) {
            f4 v = lrow[p];
            #pragma unroll
            for (int j = 0; j < 4; ++j) {
                unsigned u = __float_as_uint(v[j]);
                unsigned key = (u & 0x80000000u) ? ~u : (u | 0x80000000u);
                atomicAdd(&hist[key >> 20], 1u);
            }
        }
        __syncthreads();
        {
            const int per = NBINS / NTHR;  // 16
            const int base = t * per;
            unsigned s = 0;
            for (int i = 0; i < per; ++i) s += hist[base + i];
            seg[t] = s;
            __syncthreads();
            unsigned suff = 0;
            for (int j = NTHR - 1; j > t; --j) suff += seg[j];
            if (suff < TOPK && suff + seg[t] >= TOPK) {
                unsigned running = suff;
                for (int b = per - 1; b >= 0; --b) {
                    unsigned c = hist[base + b];
                    if (running + c >= TOPK) { binStar = (unsigned)(base + b); break; }
                    running += c;
                }
            }
        }
        __syncthreads();
        const unsigned bstar = binStar;
        for (int p = t; p < n4; p += NTHR) {
            f4 v = lrow[p];
            #pragma unroll
            for (int j = 0; j < 4; ++j) {
                float f = v[j];
                unsigned u = __float_as_uint(f);
                unsigned key = (u & 0x80000000u) ? ~u : (u | 0x80000000u);
                if ((key >> 20) >= bstar) {
                    unsigned pos = atomicAdd(&cand_cnt, 1u);
                    if (pos < CAP) { cand_v[pos] = f; cand_i[pos] = 4 * p + j; }
                }
            }
        }
        __syncthreads();
        C = (cand_cnt < (unsigned)CAP) ? (int)cand_cnt : CAP;
    }

    // ---- exact rank selection; tie-break = lower index wins (lax.top_k) ----
    for (int i = t; i < C; i += NTHR) {
        float vi = cand_v[i]; int ii = cand_i[i];
        int rank = 0;
        for (int j = 0; j < C; ++j) {
            float vj = cand_v[j]; int ij = cand_i[j];
            rank += (int)((vj > vi) || (vj == vi && ij < ii));
        }
        if (rank < TOPK) { sel_v[rank] = vi; sel_i[rank] = ii; }
    }
    __syncthreads();

    // ---- weights: exp(v - max); global softmax Z cancels under renorm ----
    if (t < 64) {
        float p = 0.f;
        if (t < TOPK) { p = expf(sel_v[t] - sel_v[0]); sel_w[t] = p; }
        for (int off = 32; off; off >>= 1) p += __shfl_down(p, off);
        if (t == 0) wsum = p;
    }
    __syncthreads();
    const float inv = 1.0f / wsum;

    // ---- gather + weighted accumulate: thread t owns float4 slots t, t+256 ----
    float4 a0 = {0.f, 0.f, 0.f, 0.f};
    float4 a1 = {0.f, 0.f, 0.f, 0.f};
    for (int k = 0; k < TOPK; ++k) {
        const float w = sel_w[k];
        const float4* erow = (const float4*)(emb + (size_t)sel_i[k] * DIM);
        float4 e0 = erow[t];
        float4 e1 = erow[t + NTHR];
        a0.x += w * e0.x; a0.y += w * e0.y; a0.z += w * e0.z; a0.w += w * e0.w;
        a1.x += w * e1.x; a1.y += w * e1.y; a1.z += w * e1.z; a1.w += w * e1.w;
    }
    a0.x *= inv; a0.y *= inv; a0.z *= inv; a0.w *= inv;
    a1.x *= inv; a1.y *= inv; a1.z *= inv; a1.w *= inv;

    float4* orow = (float4*)(out + (size_t)row * DIM);
    orow[t]        = a0;
    orow[t + NTHR] = a1;
}

extern "C" void kernel_launch(void* const* d_in, const int* in_sizes, int n_in,
                              void* d_out, int out_size, void* d_ws, size_t ws_size,
                              hipStream_t stream) {
    const float* logits = (const float*)d_in[0];
    const float* emb    = (const float*)d_in[1];
    float* out = (float*)d_out;
    const int rows = in_sizes[0] / VOCAB;   // B*T = 512
    softmix_kernel<<<rows, NTHR, 0, stream>>>(logits, emb, out);
}

// Round 3
// 86.624 us; speedup vs baseline: 2.0661x; 1.4252x over previous
//
#include <hip/hip_runtime.h>
#include <math.h>

#define VOCAB  128000
#define DIM    2048
#define TOPK   50
#define NTHR   512
#define CAP    512
#define NBINS  4096
#define THRESH 3.0f

typedef float f4 __attribute__((ext_vector_type(4)));

__global__ __launch_bounds__(NTHR, 4) void softmix_kernel(
    const float* __restrict__ logits,   // [ROWS, VOCAB]
    const float* __restrict__ emb,      // [VOCAB, DIM]
    float* __restrict__ out)            // [ROWS, DIM]
{
    __shared__ float cand_v[CAP];
    __shared__ int   cand_i[CAP];
    __shared__ unsigned int cand_cnt;
    __shared__ float sel_v[TOPK];
    __shared__ int   sel_i[TOPK];
    __shared__ float sel_w[TOPK];
    __shared__ float wsum;
    // fallback-only storage (unused on the fast path)
    __shared__ unsigned int hist[NBINS];
    __shared__ unsigned int seg[NTHR];
    __shared__ unsigned int binStar;

    const int row = blockIdx.x;
    const int t   = threadIdx.x;
    const f4* lrow = (const f4*)(logits + (size_t)row * VOCAB);
    const int n4 = VOCAB / 4;  // 32000

    if (t == 0) cand_cnt = 0u;
    __syncthreads();

    // ---- single streaming pass, unroll x2 for MLP ----
    // nontemporal: don't evict emb rows from L2/L3 with the logits stream
    #pragma unroll 1
    for (int it = 0; it < 31; ++it) {
        const int p0 = t + it * (2 * NTHR);
        f4 v0 = __builtin_nontemporal_load(lrow + p0);
        f4 v1 = __builtin_nontemporal_load(lrow + p0 + NTHR);
        #pragma unroll
        for (int j = 0; j < 4; ++j) {
            float f = v0[j];
            if (f >= THRESH) {
                unsigned pos = atomicAdd(&cand_cnt, 1u);
                if (pos < CAP) { cand_v[pos] = f; cand_i[pos] = 4 * p0 + j; }
            }
        }
        #pragma unroll
        for (int j = 0; j < 4; ++j) {
            float f = v1[j];
            if (f >= THRESH) {
                unsigned pos = atomicAdd(&cand_cnt, 1u);
                if (pos < CAP) { cand_v[pos] = f; cand_i[pos] = 4 * (p0 + NTHR) + j; }
            }
        }
    }
    {   // remainder: 31744..31999
        const int p = t + 31 * (2 * NTHR);
        if (p < n4) {
            f4 v = __builtin_nontemporal_load(lrow + p);
            #pragma unroll
            for (int j = 0; j < 4; ++j) {
                float f = v[j];
                if (f >= THRESH) {
                    unsigned pos = atomicAdd(&cand_cnt, 1u);
                    if (pos < CAP) { cand_v[pos] = f; cand_i[pos] = 4 * p + j; }
                }
            }
        }
    }
    __syncthreads();

    int C = (int)cand_cnt;

    // ---- fallback (exact for any input; never taken for N(0,1)) ----
    if (C < TOPK || C > CAP) {
        for (int i = t; i < NBINS; i += NTHR) hist[i] = 0u;
        if (t == 0) cand_cnt = 0u;
        __syncthreads();
        for (int p = t; p < n4; p += NTHR) {
            f4 v = lrow[p];
            #pragma unroll
            for (int j = 0; j < 4; ++j) {
                unsigned u = __float_as_uint(v[j]);
                unsigned key = (u & 0x80000000u) ? ~u : (u | 0x80000000u);
                atomicAdd(&hist[key >> 20], 1u);
            }
        }
        __syncthreads();
        {
            const int per = NBINS / NTHR;  // 8
            const int base = t * per;
            unsigned s = 0;
            for (int i = 0; i < per; ++i) s += hist[base + i];
            seg[t] = s;
            __syncthreads();
            unsigned suff = 0;
            for (int j = NTHR - 1; j > t; --j) suff += seg[j];
            if (suff < TOPK && suff + seg[t] >= TOPK) {
                unsigned running = suff;
                for (int b = per - 1; b >= 0; --b) {
                    unsigned c = hist[base + b];
                    if (running + c >= TOPK) { binStar = (unsigned)(base + b); break; }
                    running += c;
                }
            }
        }
        __syncthreads();
        const unsigned bstar = binStar;
        for (int p = t; p < n4; p += NTHR) {
            f4 v = lrow[p];
            #pragma unroll
            for (int j = 0; j < 4; ++j) {
                float f = v[j];
                unsigned u = __float_as_uint(f);
                unsigned key = (u & 0x80000000u) ? ~u : (u | 0x80000000u);
                if ((key >> 20) >= bstar) {
                    unsigned pos = atomicAdd(&cand_cnt, 1u);
                    if (pos < CAP) { cand_v[pos] = f; cand_i[pos] = 4 * p + j; }
                }
            }
        }
        __syncthreads();
        C = (cand_cnt < (unsigned)CAP) ? (int)cand_cnt : CAP;
    }

    // ---- exact rank selection; tie-break = lower index wins (lax.top_k) ----
    for (int i = t; i < C; i += NTHR) {
        float vi = cand_v[i]; int ii = cand_i[i];
        int rank = 0;
        for (int j = 0; j < C; ++j) {
            float vj = cand_v[j]; int ij = cand_i[j];
            rank += (int)((vj > vi) || (vj == vi && ij < ii));
        }
        if (rank < TOPK) { sel_v[rank] = vi; sel_i[rank] = ii; }
    }
    __syncthreads();

    // ---- weights: exp(v - max); global softmax Z cancels under renorm ----
    if (t < 64) {
        float p = 0.f;
        if (t < TOPK) { p = expf(sel_v[t] - sel_v[0]); sel_w[t] = p; }
        for (int off = 32; off; off >>= 1) p += __shfl_down(p, off);
        if (t == 0) wsum = p;
    }
    __syncthreads();
    const float inv = 1.0f / wsum;

    // ---- gather + weighted accumulate: thread t owns float4 slot t ----
    float4 acc = {0.f, 0.f, 0.f, 0.f};
    for (int k = 0; k < TOPK; ++k) {
        const float w = sel_w[k];
        const float4* erow = (const float4*)(emb + (size_t)sel_i[k] * DIM);
        float4 e = erow[t];
        acc.x += w * e.x; acc.y += w * e.y; acc.z += w * e.z; acc.w += w * e.w;
    }
    acc.x *= inv; acc.y *= inv; acc.z *= inv; acc.w *= inv;

    float4* orow = (float4*)(out + (size_t)row * DIM);
    orow[t] = acc;
}

extern "C" void kernel_launch(void* const* d_in, const int* in_sizes, int n_in,
                              void* d_out, int out_size, void* d_ws, size_t ws_size,
                              hipStream_t stream) {
    const float* logits = (const float*)d_in[0];
    const float* emb    = (const float*)d_in[1];
    float* out = (float*)d_out;
    const int rows = in_sizes[0] / VOCAB;   // B*T = 512
    softmix_kernel<<<rows, NTHR, 0, stream>>>(logits, emb, out);
}